// Round 11
// baseline (273.715 us; speedup 1.0000x reference)
//
#include <hip/hip_runtime.h>
#include <math.h>

#define NTOK  16384
#define HDIM  2048
#define NEXP  64
#define TOPK  6
#define TB    64            // tokens per block = lanes per wave
#define MH    128           // h per mega-chunk
#define NMEGA (HDIM / MH)   // 16
#define NHB   (MH / 32)     // 4 h-blocks (32 h) per mega

// x mega-chunks, double-buffered, slot-swizzled (slot' = s ^ (t&7)).
// Row = 128 floats = 512 B. Epilogue logits overlay after final barrier.
union SMem {
    float xs[2][TB][MH];     // 64 KB
    float lg[TB][NEXP + 1];  // 16.6 KB overlay
};

__device__ __forceinline__ void gload_lds16(const float* g, void* l) {
    __builtin_amdgcn_global_load_lds(
        (const __attribute__((address_space(1))) unsigned int*)g,
        (__attribute__((address_space(3))) unsigned int*)l, 16, 0, 0);
}

// Stage one 32KB mega-chunk: 32 wave-insts of 1KB; per wave 4. Dest linear
// (uniform base + lane*16); source slot pre-swizzled so reads can XOR-spread.
__device__ __forceinline__ void stage_mega(const float* __restrict__ x,
                                           float* xsb, int tbase, int m,
                                           int wv, int lane) {
    #pragma unroll
    for (int k = 0; k < 4; ++k) {
        const int j = 4 * wv + k;              // 1KB-unit index (wave-uniform)
        const int t = 2 * j + (lane >> 5);     // token covered by this lane
        const int s = (lane & 31) ^ (t & 7);   // pre-swizzled source slot
        gload_lds16(x + (size_t)(tbase + t) * HDIM + (size_t)m * MH + 4 * s,
                    xsb + 256 * j);
    }
}

#define FMA4(A, X, W)                      \
    A.x = fmaf(X.x, W.x, A.x);             \
    A.y = fmaf(X.y, W.y, A.y);             \
    A.z = fmaf(X.z, W.z, A.z);             \
    A.w = fmaf(X.w, W.w, A.w);

__global__ __launch_bounds__(512) void moe_gate_kernel(
        const float* __restrict__ x,
        const float* __restrict__ w,
        float* __restrict__ out)
{
    __shared__ SMem sm;

    const int tid   = threadIdx.x;
    const int lane  = tid & 63;                                  // = token
    const int wv    = __builtin_amdgcn_readfirstlane(tid >> 6);  // expert octet
    const int kk    = (lane & 7) << 4;                           // x read XOR key
    const int tbase = blockIdx.x * TB;

    // acc[e]: float4 j-partials (j=h%4, h ascending over ALL of [0,2048)) for
    // (token=lane, expert=8*wv+e). Bit-identical accumulation order to R1.
    float4 acc[8];
    #pragma unroll
    for (int e = 0; e < 8; ++e) acc[e] = make_float4(0.f, 0.f, 0.f, 0.f);

    // ---- prologue: stage mega 0 ----
    stage_mega(x, &sm.xs[0][0][0], tbase, 0, wv, lane);
    __syncthreads();

    for (int m = 0; m < NMEGA; ++m) {
        const int b = m & 1;

        // issue next mega's staging first: retires during ~4K cy of compute
        if (m + 1 < NMEGA)
            stage_mega(x, &sm.xs[b ^ 1][0][0], tbase, m + 1, wv, lane);

        // 8 swizzled read pointers for this lane's token row (static index)
        const char* xrow = (const char*)&sm.xs[b][lane][0];
        const char* xp[8];
        #pragma unroll
        for (int i = 0; i < 8; ++i) xp[i] = xrow + ((16 * i) ^ kk);

        for (int hb = 0; hb < NHB; ++hb) {
            // x window: 8 full-width b128 reads (XOR-spread, conflict-free)
            float4 xw[8];
            #pragma unroll
            for (int i = 0; i < 8; ++i)
                xw[i] = *(const float4*)(xp[i] + 128 * hb);

            // W: wave-uniform vector loads (vmcnt path; pin blocks s_load
            // scalarization -- the lgkm-collision disease of R5/R6)
            const float* wm = w + (size_t)(8 * wv) * HDIM + (size_t)m * MH + 32 * hb;
            asm volatile("" : "+v"(wm));
            #pragma unroll
            for (int e = 0; e < 8; ++e) {
                #pragma unroll
                for (int i = 0; i < 8; ++i) {
                    const float4 wq = *(const float4*)(wm + (size_t)e * HDIM + 4 * i);
                    FMA4(acc[e], xw[i], wq)
                }
            }
        }
        __syncthreads();   // one barrier per mega: staged m+1 visible, buf free
    }

    // ---- logits: np SSE combine (J0+J2)+(J1+J3); zero seams ----
    #pragma unroll
    for (int e = 0; e < 8; ++e)
        sm.lg[lane][8 * wv + e] =
            (acc[e].x + acc[e].z) + (acc[e].y + acc[e].w);
    __syncthreads();

    // ---- per-token top-6 + softmax + renorm (identical numerics to R1) ----
    if (tid < TB) {
        float val[TOPK];
        int   idx[TOPK];
        #pragma unroll
        for (int k = 0; k < TOPK; ++k) { val[k] = -3.0e38f; idx[k] = 0; }

        for (int e = 0; e < NEXP; ++e) {
            float cv = sm.lg[tid][e];
            int   ci = e;
            #pragma unroll
            for (int k = 0; k < TOPK; ++k) {
                if (cv > val[k]) {                 // strict >: lowest index wins ties
                    const float tv = val[k]; const int ti = idx[k];
                    val[k] = cv; idx[k] = ci;
                    cv = tv; ci = ti;
                }
            }
        }

        const float mx = val[0];
        float ex[TOPK];
        float s = 0.f;
        #pragma unroll
        for (int k = 0; k < TOPK; ++k) { ex[k] = expf(val[k] - mx); s += ex[k]; }
        float p[TOPK];
        float d = 0.f;
        #pragma unroll
        for (int k = 0; k < TOPK; ++k) { p[k] = ex[k] / s; d += p[k]; }
        d += 1e-20f;

        const int tg = tbase + tid;
        float* oi = out;                           // idx chunk   [NTOK*TOPK]
        float* ow = out + (size_t)NTOK * TOPK;     // weight chunk
        #pragma unroll
        for (int k = 0; k < TOPK; ++k) {
            oi[tg * TOPK + k] = (float)idx[k];
            ow[tg * TOPK + k] = p[k] / d;
        }
    }
}

extern "C" void kernel_launch(void* const* d_in, const int* in_sizes, int n_in,
                              void* d_out, int out_size, void* d_ws, size_t ws_size,
                              hipStream_t stream) {
    const float* x = (const float*)d_in[0];
    const float* w = (const float*)d_in[1];
    float* out = (float*)d_out;
    dim3 grid(NTOK / TB);   // 256 blocks = 1/CU
    dim3 block(512);        // 8 waves = 8 expert octets; lane = token
    hipLaunchKernelGGL(moe_gate_kernel, grid, block, 0, stream, x, w, out);
}

// Round 12
// 246.122 us; speedup vs baseline: 1.1121x; 1.1121x over previous
//
#include <hip/hip_runtime.h>
#include <math.h>

#define NTOK 16384
#define HDIM 2048
#define NEXP 64
#define TOPK 6
#define TB   64          // tokens per block = lanes per wave
#define CH   64          // h per chunk (16 float4 slots, 256 B per row)
#define NCH  (HDIM / CH) // 32 chunks

// x chunks double-buffered, slot-swizzled: physical slot p of row t holds
// logical slot p ^ (t&15). Staged via global_load_lds (pre-swizzled source,
// linear dest). Epilogue logits overlay.
union SMem {
    float xs[2][TB][CH];     // 32 KB
    float lg[TB][NEXP + 1];  // 16.6 KB overlay
};

__device__ __forceinline__ void gload_lds16(const float* g, void* l) {
    __builtin_amdgcn_global_load_lds(
        (const __attribute__((address_space(1))) unsigned int*)g,
        (__attribute__((address_space(3))) unsigned int*)l, 16, 0, 0);
}

// Stage one 16KB x-chunk: 16 x 1KB wave-insts, 2 per wave. Dest linear
// (uniform base + lane*16); source slot pre-swizzled by (t&15).
__device__ __forceinline__ void stage_chunk(const float* __restrict__ x,
                                            float* xsb, int tbase, int c,
                                            int wv, int lane) {
    #pragma unroll
    for (int k = 0; k < 2; ++k) {
        const int j = 2 * wv + k;            // 1KB unit (wave-uniform)
        const int t = 4 * j + (lane >> 4);   // token row this lane covers
        const int s = (lane & 15) ^ (t & 15);// pre-swizzled source slot
        gload_lds16(x + (size_t)(tbase + t) * HDIM + (size_t)c * CH + 4 * s,
                    xsb + 256 * j);
    }
}

// acc[e] += xq[i] * wq ; wq lives in SGPRs (one scalar operand per v_fma: legal)
#define FMA4(A, X, W)                      \
    A.x = fmaf(X.x, W.x, A.x);             \
    A.y = fmaf(X.y, W.y, A.y);             \
    A.z = fmaf(X.z, W.z, A.z);             \
    A.w = fmaf(X.w, W.w, A.w);

__global__ __launch_bounds__(512, 2) void moe_gate_kernel(
        const float* __restrict__ x,
        const float* __restrict__ w,
        float* __restrict__ out)
{
    __shared__ SMem sm;

    const int tid   = threadIdx.x;
    const int lane  = tid & 63;                                  // = token
    const int wv    = __builtin_amdgcn_readfirstlane(tid >> 6);  // expert octet
    const int tk    = lane & 15;                                 // x swizzle key
    const int tbase = blockIdx.x * TB;

    // acc[e]: float4 j-partials (j=h%4, h strictly ascending over [0,2048))
    // for (token=lane, expert=8*wv+e). Bit-identical accumulation to R1.
    float4 acc[8];
    #pragma unroll
    for (int e = 0; e < 8; ++e) acc[e] = make_float4(0.f, 0.f, 0.f, 0.f);

    // ---- prologue: stage chunk 0 ----
    stage_chunk(x, &sm.xs[0][0][0], tbase, 0, wv, lane);
    __syncthreads();

    for (int c = 0; c < NCH; ++c) {
        const int b = c & 1;

        // issue next chunk's staging first (vmcnt retires under ~1000cy of
        // compute; barrier drain then free). Other buffer's readers done.
        if (c + 1 < NCH)
            stage_chunk(x, &sm.xs[b ^ 1][0][0], tbase, c + 1, wv, lane);

        const char* xrow = (const char*)&sm.xs[b][lane][0];

        // two half-chunks: batch 8 ds_read_b128, then pure s_load + v_fma.
        // lgkm FIFO: ds_reads drain once at half-top (data needed anyway),
        // then only s_loads -- no per-step cross-path coupling (R5 lesson).
        #pragma unroll
        for (int half = 0; half < 2; ++half) {
            float4 xq[8];
            #pragma unroll
            for (int i = 0; i < 8; ++i)
                xq[i] = *(const float4*)(xrow + (((8 * half + i) ^ tk) << 4));

            const float* wc = w + (size_t)c * CH + 32 * half;
            #pragma unroll
            for (int e = 0; e < 8; ++e) {
                const float* we = wc + (size_t)(8 * wv + e) * HDIM;
                #pragma unroll
                for (int i = 0; i < 8; ++i) {
                    const float4 wq = *(const float4*)(we + 4 * i); // s_load
                    FMA4(acc[e], xq[i], wq)
                }
            }
        }
        __syncthreads();   // one barrier per chunk
    }

    // ---- logits: np SSE combine (J0+J2)+(J1+J3); zero seams ----
    #pragma unroll
    for (int e = 0; e < 8; ++e)
        sm.lg[lane][8 * wv + e] =
            (acc[e].x + acc[e].z) + (acc[e].y + acc[e].w);
    __syncthreads();

    // ---- per-token top-6 + softmax + renorm (identical numerics to R1) ----
    if (tid < TB) {
        float val[TOPK];
        int   idx[TOPK];
        #pragma unroll
        for (int k = 0; k < TOPK; ++k) { val[k] = -3.0e38f; idx[k] = 0; }

        for (int e = 0; e < NEXP; ++e) {
            float cv = sm.lg[tid][e];
            int   ci = e;
            #pragma unroll
            for (int k = 0; k < TOPK; ++k) {
                if (cv > val[k]) {                 // strict >: lowest index wins ties
                    const float tv = val[k]; const int ti = idx[k];
                    val[k] = cv; idx[k] = ci;
                    cv = tv; ci = ti;
                }
            }
        }

        const float mx = val[0];
        float ex[TOPK];
        float s = 0.f;
        #pragma unroll
        for (int k = 0; k < TOPK; ++k) { ex[k] = expf(val[k] - mx); s += ex[k]; }
        float p[TOPK];
        float d = 0.f;
        #pragma unroll
        for (int k = 0; k < TOPK; ++k) { p[k] = ex[k] / s; d += p[k]; }
        d += 1e-20f;

        const int tg = tbase + tid;
        float* oi = out;                           // idx chunk   [NTOK*TOPK]
        float* ow = out + (size_t)NTOK * TOPK;     // weight chunk
        #pragma unroll
        for (int k = 0; k < TOPK; ++k) {
            oi[tg * TOPK + k] = (float)idx[k];
            ow[tg * TOPK + k] = p[k] / d;
        }
    }
}

extern "C" void kernel_launch(void* const* d_in, const int* in_sizes, int n_in,
                              void* d_out, int out_size, void* d_ws, size_t ws_size,
                              hipStream_t stream) {
    const float* x = (const float*)d_in[0];
    const float* w = (const float*)d_in[1];
    float* out = (float*)d_out;
    dim3 grid(NTOK / TB);   // 256 blocks = 1/CU, 8 waves/CU
    dim3 block(512);        // 8 waves = 8 expert octets; lane = token
    hipLaunchKernelGGL(moe_gate_kernel, grid, block, 0, stream, x, w, out);
}